// Round 12
// baseline (103.200 us; speedup 1.0000x reference)
//
#include <hip/hip_runtime.h>
#include <hip/hip_bf16.h>

// FirDownsample: y = depthwise FIR(4x4 separable [1,3,3,1]) on x (pad 2),
// out = conv3x3(y, w), stride 2.  x:(16,320,64,64) f32, out:(16,320,32,32) f32.
//
// R12: attack instruction floors derived from clean totals:
//  fir : bf16 vlds (17.9KB -> 8 blocks/CU full TLP) + 2-c-per-thread horiz
//        (5 LDS reads per 2 outputs instead of 4 per 1).
//  conv: 2-wave block, wave M64xN32 (A-frag reuse x2: 27 ds_read_b128 per
//        72 MFMA instead of per 36) -> DS-throughput bound halves.
//   K1 fir_kernel : x -> y[n][cc=10][65][65][32ci] bf16
//   K2 wt2_kernel : w -> wt2[tap][cc][q][co][8ci] bf16
//   K3 conv_kernel: M64xN64 block (128 thr), B kw-rolling regs, A via global_load_lds.

typedef short bf16x8_t __attribute__((ext_vector_type(8)));
typedef float f32x4 __attribute__((ext_vector_type(4)));
typedef unsigned int u32x4 __attribute__((ext_vector_type(4)));
typedef __attribute__((address_space(1))) const unsigned int* as1_u32p;
typedef __attribute__((address_space(3))) unsigned int* as3_u32p;

#define NI 16
#define CCH 320
#define HW 64
#define HY 65
#define HY2 4225           // 65*65
#define CCSTEP 135200      // 4225*32 shorts per cc-plane

// ---------------- K1: separable FIR, x(f32) -> y bf16 [n][cc][r][c][32] ----------------
// block = (n, 4-row band, cc). vert: vlds[j4][ci32][70] bf16 (17.9KB -> 8 blocks/CU).
// horiz: task = (j, c-pair, octet s): 5 reads/k -> 2 outputs; paired 16B stores.
__global__ __launch_bounds__(256) void fir_kernel(const float* __restrict__ x,
                                                  const float* __restrict__ fir_k,
                                                  __hip_bfloat16* __restrict__ yt) {
    __shared__ unsigned short vlds[4 * 32 * 70];  // [j][ci][cc70] bf16 : 17,920 B
    int bx = blockIdx.x;
    int n    = bx / 170;
    int rem  = bx % 170;
    int band = rem / 10;
    int cc   = rem % 10;
    int r0   = band * 4;

    float f0 = fir_k[0] + fir_k[1] + fir_k[2] + fir_k[3];
    float f1 = fir_k[4] + fir_k[5] + fir_k[6] + fir_k[7];
    float f2 = fir_k[8] + fir_k[9] + fir_k[10] + fir_k[11];
    float f3 = fir_k[12] + fir_k[13] + fir_k[14] + fir_k[15];

    int tid = threadIdx.x;
    int lane = tid & 63;   // = w (vert)
    int g = tid >> 6;      // wave id

    // vertical pass: vlds[j][cis][w+2] = bf16( sum_a f[a] * x[r0+j-2+a][w] )
    for (int cis = g; cis < 32; cis += 4) {
        int ci = cc * 32 + cis;
        const float* xb = x + (size_t)(n * CCH + ci) * HW * HW;
        float xr[7];
#pragma unroll
        for (int t = 0; t < 7; ++t) {
            int row = r0 + t - 2;
            xr[t] = (row >= 0 && row < HW) ? xb[row * HW + lane] : 0.f;
        }
#pragma unroll
        for (int j = 0; j < 4; ++j) {
            float v = f0 * xr[j] + f1 * xr[j + 1] + f2 * xr[j + 2] + f3 * xr[j + 3];
            unsigned short* vrow = vlds + (j * 32 + cis) * 70;
            vrow[lane + 2] = __bfloat16_as_ushort(__float2bfloat16(v));
            if (lane < 2)   vrow[lane] = 0;         // cc 0,1
            if (lane >= 62) vrow[lane + 4] = 0;     // cc 66,67
        }
    }
    __syncthreads();

    // horizontal pass: task = (j, pair pp, octet s); 528 tasks
    unsigned short* yu = (unsigned short*)yt;
    size_t plane = (size_t)(n * 10 + cc) * HY2;
#pragma unroll
    for (int it = 0; it < 3; ++it) {
        int task = it * 256 + tid;
        if (task < 528) {
            int s  = task & 3;
            int t2 = task >> 2;          // 0..131
            int j  = t2 / 33;
            int pp = t2 % 33;
            int c  = 2 * pp;
            int r  = r0 + j;
            if (r < HY) {
                const unsigned short* vb = vlds + (j * 32 + s * 8) * 70 + c;
                bool pair = (pp < 32);
                float a0[8], a1[8];
#pragma unroll
                for (int k = 0; k < 8; ++k) {
                    const unsigned short* vr = vb + k * 70;
                    float v0 = __bfloat162float(__ushort_as_bfloat16(vr[0]));
                    float v1 = __bfloat162float(__ushort_as_bfloat16(vr[1]));
                    float v2 = __bfloat162float(__ushort_as_bfloat16(vr[2]));
                    float v3 = __bfloat162float(__ushort_as_bfloat16(vr[3]));
                    a0[k] = f0 * v0 + f1 * v1 + f2 * v2 + f3 * v3;
                    if (pair) {
                        float v4 = __bfloat162float(__ushort_as_bfloat16(vr[4]));
                        a1[k] = f0 * v1 + f1 * v2 + f2 * v3 + f3 * v4;
                    }
                }
                unsigned int w0[4];
#pragma unroll
                for (int h = 0; h < 4; ++h) {
                    unsigned int lo = __bfloat16_as_ushort(__float2bfloat16(a0[2 * h]));
                    unsigned int hi = __bfloat16_as_ushort(__float2bfloat16(a0[2 * h + 1]));
                    w0[h] = lo | (hi << 16);
                }
                size_t base = (plane + (size_t)r * HY + c) * 32 + s * 8;
                *(u32x4*)(yu + base) = (u32x4){w0[0], w0[1], w0[2], w0[3]};
                if (pair) {
                    unsigned int w1[4];
#pragma unroll
                    for (int h = 0; h < 4; ++h) {
                        unsigned int lo = __bfloat16_as_ushort(__float2bfloat16(a1[2 * h]));
                        unsigned int hi = __bfloat16_as_ushort(__float2bfloat16(a1[2 * h + 1]));
                        w1[h] = lo | (hi << 16);
                    }
                    *(u32x4*)(yu + base + 32) = (u32x4){w1[0], w1[1], w1[2], w1[3]};
                }
            }
        }
    }
}

// ---------------- K2: w (co,ci,3,3) f32 -> wt2[tap][cc][q][co][8] bf16 ----------------
__global__ __launch_bounds__(256) void wt2_kernel(const float* __restrict__ w,
                                                  __hip_bfloat16* __restrict__ wt) {
    int idx = blockIdx.x * 256 + threadIdx.x;
    if (idx < 9 * CCH * CCH) {
        int j  = idx & 7;
        int co = (idx >> 3) % CCH;
        int t2 = idx / 2560;          // tap*40 + cc*4 + q
        int q  = t2 & 3;
        int cc = (t2 >> 2) % 10;
        int tap = t2 / 40;
        int ci = cc * 32 + q * 8 + j;
        wt[idx] = __float2bfloat16(w[(co * CCH + ci) * 9 + tap]);
    }
}

// ---------------- K3: MFMA conv, M64 x N64, TWO waves (M64xN32 each) ----------------
// grid = (n*5 + cb)*16 + sp ; wave wid owns co chunk wid*32 (nf 0..1).
// LDS: dbuf of 1536 16B-units (80B row pitch scheme, conflict-free b128, proven).
// A staged via global_load_lds; B kw-rolling in registers (no load-use stalls).
// Per wave per cc: 27 ds_read_b128 feed 72 MFMA (was 36) -> DS bound halved.
__global__ __launch_bounds__(128) void conv_kernel(const __hip_bfloat16* __restrict__ yt,
                                                   const __hip_bfloat16* __restrict__ wt2,
                                                   float* __restrict__ out) {
    __shared__ short ylds[2][1536 * 8];   // 2 x 24,576 B

    int bx = blockIdx.x;
    int sp = bx & 15;
    int t  = bx >> 4;
    int cb = t % 5;
    int n  = t / 5;
    int co0 = cb * 64;
    int oh0 = (sp >> 1) * 4;
    int ow0 = (sp & 1) * 16;

    int tid = threadIdx.x;        // 0..127
    int lane = tid & 63;
    int wid = tid >> 6;           // 0..1
    int q = lane >> 4, lc = lane & 15;

    const unsigned short* ytu = (const unsigned short*)yt;
    const unsigned short* wtu = (const unsigned short*)wt2;

    // per-lane global source offsets (shorts) for staging units, cc=0
    int ybase = (n * 10 * HY2 + (2 * oh0) * HY + 2 * ow0) * 32;
    int goff[12];
#pragma unroll
    for (int k = 0; k < 12; ++k) {
        int u = k * 128 + tid;
        int uc = (u < 1485) ? u : 1484;    // tail: safe dup, lands in pad units
        int p = uc / 5, s = uc - p * 5;
        if (s == 4) s = 3;                 // row-pad unit: dup of unit 3, never read
        int pr = p / 33, pc = p - pr * 33;
        goff[k] = ybase + (pr * HY + pc) * 32 + s * 8;
    }

    const unsigned short* wbl = wtu + q * 2560 + (size_t)(co0 + wid * 32 + lc) * 8;
    const int aoff = (2 * lc) * 40 + q * 8;   // short-index within buffer

    f32x4 acc[4][2];
#pragma unroll
    for (int i = 0; i < 4; ++i)
#pragma unroll
        for (int j = 0; j < 2; ++j) acc[i][j] = (f32x4){0.f, 0.f, 0.f, 0.f};

    bf16x8_t bq[6];   // current kw-stage B frags [kh][nf]

#define GLDS(buf, K, ccidx)                                                            \
    __builtin_amdgcn_global_load_lds(                                                  \
        (as1_u32p)(ytu + goff[K] + (ccidx) * CCSTEP),                                  \
        (as3_u32p)(&ylds[buf][(size_t)((K) * 128 + wid * 64) * 8]), 16, 0, 0)

#define LOADB(dst, ccidx, kw)                                                          \
    {                                                                                  \
        const unsigned short* wcc_ = wbl + (ccidx) * 10240;                            \
        _Pragma("unroll")                                                              \
        for (int kh_ = 0; kh_ < 3; ++kh_)                                              \
            _Pragma("unroll")                                                          \
            for (int nf_ = 0; nf_ < 2; ++nf_)                                          \
                dst[kh_ * 2 + nf_] = *(const bf16x8_t*)(wcc_ + (kh_ * 3 + (kw)) * 102400 + nf_ * 128); \
    }

    // prologue: stage A(0) -> buf0, load B(cc0, kw0)
#pragma unroll
    for (int k = 0; k < 12; ++k) GLDS(0, k, 0);
    LOADB(bq, 0, 0);
    __syncthreads();

    for (int cc = 0; cc < 10; ++cc) {
        const short* buf = &ylds[cc & 1][0];
        // prefetch next A-tile into other buffer (in flight across compute)
        if (cc < 9) {
#pragma unroll
            for (int k = 0; k < 12; ++k) GLDS((cc & 1) ^ 1, k, cc + 1);
        }
#pragma unroll
        for (int kw = 0; kw < 3; ++kw) {
            bf16x8_t af[9];
#pragma unroll
            for (int r = 0; r < 9; ++r)
                af[r] = *(const bf16x8_t*)(buf + aoff + (r * 33 + kw) * 40);
            bf16x8_t bn[6];
            if (kw < 2) {
                LOADB(bn, cc, kw + 1);
            } else if (cc < 9) {
                LOADB(bn, cc + 1, 0);
            }
#pragma unroll
            for (int kh = 0; kh < 3; ++kh)
#pragma unroll
                for (int mf = 0; mf < 4; ++mf)
#pragma unroll
                    for (int nf = 0; nf < 2; ++nf)
                        acc[mf][nf] = __builtin_amdgcn_mfma_f32_16x16x32_bf16(
                            bq[kh * 2 + nf], af[2 * mf + kh], acc[mf][nf], 0, 0, 0);
#pragma unroll
            for (int i = 0; i < 6; ++i) bq[i] = bn[i];
        }
        __syncthreads();   // A(cc+1) in LDS (vmcnt drained), buf roles swap
    }
#undef GLDS
#undef LOADB

    // epilogue: D[row=co][col=m]; coalesced 64B segments
#pragma unroll
    for (int mf = 0; mf < 4; ++mf) {
        int oh = oh0 + mf;
        int ow = ow0 + lc;
#pragma unroll
        for (int nf = 0; nf < 2; ++nf) {
#pragma unroll
            for (int rg = 0; rg < 4; ++rg) {
                int co = co0 + wid * 32 + nf * 16 + q * 4 + rg;
                out[((n * CCH + co) * 32 + oh) * 32 + ow] = acc[mf][nf][rg];
            }
        }
    }
}

// ---------------- Fallback: naive direct (correct, slow) ----------------
__global__ __launch_bounds__(256) void naive_kernel(const float* __restrict__ x,
                                                    const float* __restrict__ w,
                                                    const float* __restrict__ fk,
                                                    float* __restrict__ out) {
    int idx = blockIdx.x * 256 + threadIdx.x;
    if (idx >= NI * CCH * 32 * 32) return;
    int ow = idx & 31;
    int oh = (idx >> 5) & 31;
    int co = (idx >> 10) % CCH;
    int n = (idx >> 10) / CCH;
    float f0 = fk[0] + fk[1] + fk[2] + fk[3];
    float f1 = fk[4] + fk[5] + fk[6] + fk[7];
    float f2 = fk[8] + fk[9] + fk[10] + fk[11];
    float f3 = fk[12] + fk[13] + fk[14] + fk[15];
    float fv[4] = {f0, f1, f2, f3};
    float acc = 0.f;
    for (int ci = 0; ci < CCH; ++ci) {
        const float* xb = x + (size_t)(n * CCH + ci) * HW * HW;
        const float* wb = w + (size_t)(co * CCH + ci) * 9;
#pragma unroll
        for (int u = 0; u < 3; ++u) {
            int yr = 2 * oh + u;
#pragma unroll
            for (int v = 0; v < 3; ++v) {
                int yc = 2 * ow + v;
                float s = 0.f;
#pragma unroll
                for (int a = 0; a < 4; ++a) {
                    int xrw = yr - 2 + a;
                    if (xrw < 0 || xrw >= HW) continue;
                    float t = 0.f;
#pragma unroll
                    for (int b = 0; b < 4; ++b) {
                        int xc = yc - 2 + b;
                        if (xc >= 0 && xc < HW) t += fv[b] * xb[xrw * HW + xc];
                    }
                    s += fv[a] * t;
                }
                acc += wb[u * 3 + v] * s;
            }
        }
    }
    out[idx] = acc;
}

extern "C" void kernel_launch(void* const* d_in, const int* in_sizes, int n_in,
                              void* d_out, int out_size, void* d_ws, size_t ws_size,
                              hipStream_t stream) {
    const float* x = (const float*)d_in[0];
    const float* w = (const float*)d_in[1];
    const float* fk = (const float*)d_in[2];
    float* out = (float*)d_out;

    const size_t ybytes = (size_t)NI * 10 * HY2 * 32 * 2;     // 43,264,000
    const size_t wtoff = ybytes;
    const size_t need = wtoff + (size_t)9 * CCH * CCH * 2;    // 45,107,200

    if (ws_size >= need) {
        __hip_bfloat16* yt = (__hip_bfloat16*)d_ws;
        __hip_bfloat16* wt = (__hip_bfloat16*)((char*)d_ws + wtoff);
        fir_kernel<<<16 * 17 * 10, 256, 0, stream>>>(x, fk, yt);
        wt2_kernel<<<(9 * CCH * CCH + 255) / 256, 256, 0, stream>>>(w, wt);
        conv_kernel<<<16 * 5 * 16, 128, 0, stream>>>(yt, wt, out);
    } else {
        naive_kernel<<<(NI * CCH * 32 * 32 + 255) / 256, 256, 0, stream>>>(x, w, fk, out);
    }
}

// Round 13
// 76.131 us; speedup vs baseline: 1.3556x; 1.3556x over previous
//
#include <hip/hip_runtime.h>
#include <hip/hip_bf16.h>

// FirDownsample: y = depthwise FIR(4x4 separable [1,3,3,1]) on x (pad 2),
// out = conv3x3(y, w), stride 2.  x:(16,320,64,64) f32, out:(16,320,32,32) f32.
//
// R13: compose proven winners. conv = byte-exact R10 (measured ~23us, 3x).
// fir = R12 structure (bf16 vlds, 2-c-per-thread horiz) with 8-row bands:
// x overfetch 1.75x -> 1.375x, HBM 190 -> 158MB, floor ~25us. vlds 35.8KB
// still 4 blocks/CU.
//   K1 fir_kernel : x -> y[n][cc=10][65][65][32ci] bf16
//   K2 wt2_kernel : w -> wt2[tap][cc][q][co][8ci] bf16
//   K3 conv_kernel: M64xN64 block, 4 waves M64xN16, B reg-dbuf, A via global_load_lds.

typedef short bf16x8_t __attribute__((ext_vector_type(8)));
typedef float f32x4 __attribute__((ext_vector_type(4)));
typedef unsigned int u32x4 __attribute__((ext_vector_type(4)));
typedef __attribute__((address_space(1))) const unsigned int* as1_u32p;
typedef __attribute__((address_space(3))) unsigned int* as3_u32p;

#define NI 16
#define CCH 320
#define HW 64
#define HY 65
#define HY2 4225           // 65*65
#define CCSTEP 135200      // 4225*32 shorts per cc-plane

// ---------------- K1: separable FIR, x(f32) -> y bf16 [n][cc][r][c][32] ----------------
// block = (n, 8-row band, cc). vert: vlds[j8][ci32][70] bf16 (35.8KB -> 4 blocks/CU).
// horiz: task = (j, c-pair, octet s): 5 reads -> 2 outputs; paired 16B stores.
__global__ __launch_bounds__(256) void fir_kernel(const float* __restrict__ x,
                                                  const float* __restrict__ fir_k,
                                                  __hip_bfloat16* __restrict__ yt) {
    __shared__ unsigned short vlds[8 * 32 * 70];  // [j][ci][cc70] bf16 : 35,840 B
    int bx = blockIdx.x;
    int n    = bx / 90;
    int rem  = bx % 90;
    int band = rem / 10;          // 0..8
    int cc   = rem % 10;
    int r0   = band * 8;

    float f0 = fir_k[0] + fir_k[1] + fir_k[2] + fir_k[3];
    float f1 = fir_k[4] + fir_k[5] + fir_k[6] + fir_k[7];
    float f2 = fir_k[8] + fir_k[9] + fir_k[10] + fir_k[11];
    float f3 = fir_k[12] + fir_k[13] + fir_k[14] + fir_k[15];

    int tid = threadIdx.x;
    int lane = tid & 63;   // = w (vert)
    int g = tid >> 6;      // wave id

    // vertical pass: vlds[j][cis][w+2] = bf16( sum_a f[a] * x[r0+j-2+a][w] )
    for (int cis = g; cis < 32; cis += 4) {
        int ci = cc * 32 + cis;
        const float* xb = x + (size_t)(n * CCH + ci) * HW * HW;
        float xr[11];
#pragma unroll
        for (int t = 0; t < 11; ++t) {
            int row = r0 + t - 2;
            xr[t] = (row >= 0 && row < HW) ? xb[row * HW + lane] : 0.f;
        }
#pragma unroll
        for (int j = 0; j < 8; ++j) {
            float v = f0 * xr[j] + f1 * xr[j + 1] + f2 * xr[j + 2] + f3 * xr[j + 3];
            unsigned short* vrow = vlds + (j * 32 + cis) * 70;
            vrow[lane + 2] = __bfloat16_as_ushort(__float2bfloat16(v));
            if (lane < 2)   vrow[lane] = 0;         // cc 0,1
            if (lane >= 62) vrow[lane + 4] = 0;     // cc 66,67
        }
    }
    __syncthreads();

    // horizontal pass: task = (j, pair pp, octet s); 1056 tasks (8j x 33pp x 4s)
    unsigned short* yu = (unsigned short*)yt;
    size_t plane = (size_t)(n * 10 + cc) * HY2;
#pragma unroll
    for (int it = 0; it < 5; ++it) {
        int task = it * 256 + tid;
        if (task < 1056) {
            int s  = task & 3;
            int t2 = task >> 2;          // 0..263
            int j  = t2 / 33;
            int pp = t2 % 33;
            int c  = 2 * pp;
            int r  = r0 + j;
            if (r < HY) {
                const unsigned short* vb = vlds + (j * 32 + s * 8) * 70 + c;
                bool pair = (pp < 32);
                float a0[8], a1[8];
#pragma unroll
                for (int k = 0; k < 8; ++k) {
                    const unsigned short* vr = vb + k * 70;
                    float v0 = __bfloat162float(__ushort_as_bfloat16(vr[0]));
                    float v1 = __bfloat162float(__ushort_as_bfloat16(vr[1]));
                    float v2 = __bfloat162float(__ushort_as_bfloat16(vr[2]));
                    float v3 = __bfloat162float(__ushort_as_bfloat16(vr[3]));
                    a0[k] = f0 * v0 + f1 * v1 + f2 * v2 + f3 * v3;
                    if (pair) {
                        float v4 = __bfloat162float(__ushort_as_bfloat16(vr[4]));
                        a1[k] = f0 * v1 + f1 * v2 + f2 * v3 + f3 * v4;
                    }
                }
                unsigned int w0[4];
#pragma unroll
                for (int h = 0; h < 4; ++h) {
                    unsigned int lo = __bfloat16_as_ushort(__float2bfloat16(a0[2 * h]));
                    unsigned int hi = __bfloat16_as_ushort(__float2bfloat16(a0[2 * h + 1]));
                    w0[h] = lo | (hi << 16);
                }
                size_t base = (plane + (size_t)r * HY + c) * 32 + s * 8;
                *(u32x4*)(yu + base) = (u32x4){w0[0], w0[1], w0[2], w0[3]};
                if (pair) {
                    unsigned int w1[4];
#pragma unroll
                    for (int h = 0; h < 4; ++h) {
                        unsigned int lo = __bfloat16_as_ushort(__float2bfloat16(a1[2 * h]));
                        unsigned int hi = __bfloat16_as_ushort(__float2bfloat16(a1[2 * h + 1]));
                        w1[h] = lo | (hi << 16);
                    }
                    *(u32x4*)(yu + base + 32) = (u32x4){w1[0], w1[1], w1[2], w1[3]};
                }
            }
        }
    }
}

// ---------------- K2: w (co,ci,3,3) f32 -> wt2[tap][cc][q][co][8] bf16 ----------------
__global__ __launch_bounds__(256) void wt2_kernel(const float* __restrict__ w,
                                                  __hip_bfloat16* __restrict__ wt) {
    int idx = blockIdx.x * 256 + threadIdx.x;
    if (idx < 9 * CCH * CCH) {
        int j  = idx & 7;
        int co = (idx >> 3) % CCH;
        int t2 = idx / 2560;          // tap*40 + cc*4 + q
        int q  = t2 & 3;
        int cc = (t2 >> 2) % 10;
        int tap = t2 / 40;
        int ci = cc * 32 + q * 8 + j;
        wt[idx] = __float2bfloat16(w[(co * CCH + ci) * 9 + tap]);
    }
}

// ---------------- K3: MFMA conv, M64 x N64, waves M64xN16, B reg-dbuf (exact R10) ----------------
// grid = (n*5 + cb)*16 + sp ; wave wid owns co chunk wid*16.
// LDS: dbuf of 1536 16B-units; pos p = units 5p..5p+3 (+1 pad) -> 80B row pitch,
// conflict-free b128 reads. A staged via global_load_lds width 16.
__global__ __launch_bounds__(256, 3) void conv_kernel(const __hip_bfloat16* __restrict__ yt,
                                                      const __hip_bfloat16* __restrict__ wt2,
                                                      float* __restrict__ out) {
    __shared__ short ylds[2][1536 * 8];   // 2 x 24,576 B

    int bx = blockIdx.x;
    int sp = bx & 15;
    int t  = bx >> 4;
    int cb = t % 5;
    int n  = t / 5;
    int co0 = cb * 64;
    int oh0 = (sp >> 1) * 4;
    int ow0 = (sp & 1) * 16;

    int tid = threadIdx.x;
    int lane = tid & 63;
    int wid = tid >> 6;
    int q = lane >> 4, lc = lane & 15;

    const unsigned short* ytu = (const unsigned short*)yt;
    const unsigned short* wtu = (const unsigned short*)wt2;

    // per-lane global source offsets (shorts) for staging units, cc=0
    int ybase = (n * 10 * HY2 + (2 * oh0) * HY + 2 * ow0) * 32;
    int goff[6];
#pragma unroll
    for (int k = 0; k < 6; ++k) {
        int u = k * 256 + tid;
        int uc = (u < 1485) ? u : 1484;    // tail: safe dup, lands in pad units
        int p = uc / 5, s = uc - p * 5;
        if (s == 4) s = 3;                 // row-pad unit: dup of unit 3, never read
        int pr = p / 33, pc = p - pr * 33;
        goff[k] = ybase + (pr * HY + pc) * 32 + s * 8;
    }

    const unsigned short* wbl = wtu + q * 2560 + (size_t)(co0 + wid * 16 + lc) * 8;
    const int aoff = (2 * lc) * 40 + q * 8;   // short-index within buffer

    f32x4 acc[4];
#pragma unroll
    for (int i = 0; i < 4; ++i) acc[i] = (f32x4){0.f, 0.f, 0.f, 0.f};

    bf16x8_t bfr[2][9];

    // wave-uniform LDS unit base for stage issue k: (k*256 + wid*64) units
#define GLDS(buf, K, ccidx)                                                            \
    __builtin_amdgcn_global_load_lds(                                                  \
        (as1_u32p)(ytu + goff[K] + (ccidx) * CCSTEP),                                  \
        (as3_u32p)(&ylds[buf][(size_t)((K) * 256 + wid * 64) * 8]), 16, 0, 0)

    // prologue: stage A(0) -> buf0, load B(0) -> bfr[0]
#pragma unroll
    for (int k = 0; k < 6; ++k) GLDS(0, k, 0);
#pragma unroll
    for (int kk = 0; kk < 9; ++kk)
        bfr[0][kk] = *(const bf16x8_t*)(wbl + kk * 102400);
    __syncthreads();

    auto compute = [&](const short* buf, const bf16x8_t* b) {
#pragma unroll
        for (int kw = 0; kw < 3; ++kw) {
            bf16x8_t af[9];
#pragma unroll
            for (int r = 0; r < 9; ++r)
                af[r] = *(const bf16x8_t*)(buf + aoff + (r * 33 + kw) * 40);
#pragma unroll
            for (int kh = 0; kh < 3; ++kh)
#pragma unroll
                for (int mf = 0; mf < 4; ++mf)
                    acc[mf] = __builtin_amdgcn_mfma_f32_16x16x32_bf16(
                        b[kh * 3 + kw], af[2 * mf + kh], acc[mf], 0, 0, 0);
        }
    };

    for (int tt = 0; tt < 5; ++tt) {
        int cc0 = 2 * tt, cc1 = 2 * tt + 1;
        // ---- even cc: compute from buf0/bfr[0]; prefetch cc0+1 -> buf1/bfr[1]
        {
#pragma unroll
            for (int k = 0; k < 6; ++k) GLDS(1, k, cc0 + 1);
            const unsigned short* wnx = wbl + (cc0 + 1) * 10240;
#pragma unroll
            for (int kk = 0; kk < 9; ++kk)
                bfr[1][kk] = *(const bf16x8_t*)(wnx + kk * 102400);
            compute(&ylds[0][0], bfr[0]);
            __syncthreads();   // drains vmcnt -> A(cc0+1) in LDS, bfr[1] ready
        }
        // ---- odd cc: compute from buf1/bfr[1]; prefetch cc1+1 -> buf0/bfr[0]
        {
            if (cc1 < 9) {
#pragma unroll
                for (int k = 0; k < 6; ++k) GLDS(0, k, cc1 + 1);
                const unsigned short* wnx = wbl + (cc1 + 1) * 10240;
#pragma unroll
                for (int kk = 0; kk < 9; ++kk)
                    bfr[0][kk] = *(const bf16x8_t*)(wnx + kk * 102400);
            }
            compute(&ylds[1][0], bfr[1]);
            if (cc1 < 9) __syncthreads();
        }
    }
#undef GLDS

    // epilogue: D[row=co][col=m]; coalesced 64B segments
#pragma unroll
    for (int mf = 0; mf < 4; ++mf) {
        int oh = oh0 + mf;
        int ow = ow0 + lc;
#pragma unroll
        for (int rg = 0; rg < 4; ++rg) {
            int co = co0 + wid * 16 + q * 4 + rg;
            out[((n * CCH + co) * 32 + oh) * 32 + ow] = acc[mf][rg];
        }
    }
}

// ---------------- Fallback: naive direct (correct, slow) ----------------
__global__ __launch_bounds__(256) void naive_kernel(const float* __restrict__ x,
                                                    const float* __restrict__ w,
                                                    const float* __restrict__ fk,
                                                    float* __restrict__ out) {
    int idx = blockIdx.x * 256 + threadIdx.x;
    if (idx >= NI * CCH * 32 * 32) return;
    int ow = idx & 31;
    int oh = (idx >> 5) & 31;
    int co = (idx >> 10) % CCH;
    int n = (idx >> 10) / CCH;
    float f0 = fk[0] + fk[1] + fk[2] + fk[3];
    float f1 = fk[4] + fk[5] + fk[6] + fk[7];
    float f2 = fk[8] + fk[9] + fk[10] + fk[11];
    float f3 = fk[12] + fk[13] + fk[14] + fk[15];
    float fv[4] = {f0, f1, f2, f3};
    float acc = 0.f;
    for (int ci = 0; ci < CCH; ++ci) {
        const float* xb = x + (size_t)(n * CCH + ci) * HW * HW;
        const float* wb = w + (size_t)(co * CCH + ci) * 9;
#pragma unroll
        for (int u = 0; u < 3; ++u) {
            int yr = 2 * oh + u;
#pragma unroll
            for (int v = 0; v < 3; ++v) {
                int yc = 2 * ow + v;
                float s = 0.f;
#pragma unroll
                for (int a = 0; a < 4; ++a) {
                    int xrw = yr - 2 + a;
                    if (xrw < 0 || xrw >= HW) continue;
                    float t = 0.f;
#pragma unroll
                    for (int b = 0; b < 4; ++b) {
                        int xc = yc - 2 + b;
                        if (xc >= 0 && xc < HW) t += fv[b] * xb[xrw * HW + xc];
                    }
                    s += fv[a] * t;
                }
                acc += wb[u * 3 + v] * s;
            }
        }
    }
    out[idx] = acc;
}

extern "C" void kernel_launch(void* const* d_in, const int* in_sizes, int n_in,
                              void* d_out, int out_size, void* d_ws, size_t ws_size,
                              hipStream_t stream) {
    const float* x = (const float*)d_in[0];
    const float* w = (const float*)d_in[1];
    const float* fk = (const float*)d_in[2];
    float* out = (float*)d_out;

    const size_t ybytes = (size_t)NI * 10 * HY2 * 32 * 2;     // 43,264,000
    const size_t wtoff = ybytes;
    const size_t need = wtoff + (size_t)9 * CCH * CCH * 2;    // 45,107,200

    if (ws_size >= need) {
        __hip_bfloat16* yt = (__hip_bfloat16*)d_ws;
        __hip_bfloat16* wt = (__hip_bfloat16*)((char*)d_ws + wtoff);
        fir_kernel<<<16 * 9 * 10, 256, 0, stream>>>(x, fk, yt);
        wt2_kernel<<<(9 * CCH * CCH + 255) / 256, 256, 0, stream>>>(w, wt);
        conv_kernel<<<16 * 5 * 16, 256, 0, stream>>>(yt, wt, out);
    } else {
        naive_kernel<<<(NI * CCH * 32 * 32 + 255) / 256, 256, 0, stream>>>(x, w, fk, out);
    }
}